// Round 1
// baseline (196.108 us; speedup 1.0000x reference)
//
#include <hip/hip_runtime.h>
#include <math.h>

// AdaptiveTripletMarginLoss: B=65536 rows, D=256 fp32.
// One wave (64 lanes) per row: lane i loads float4 -> 64*16B = 1KiB = full row.
// Memory-bound: 192 MiB read, ~32us floor at 6.3 TB/s.

#define D 256
#define TPB 256              // 4 waves per block
#define WPB (TPB / 64)
#define NBLOCKS 2048         // 8192 waves, 8 rows/wave grid-stride

__global__ __launch_bounds__(TPB, 8) void triplet_partial(
    const float* __restrict__ a, const float* __restrict__ p,
    const float* __restrict__ n, float* __restrict__ partial, int B)
{
    const int lane = threadIdx.x & 63;
    const int waveInBlock = threadIdx.x >> 6;
    const int waveId = blockIdx.x * WPB + waveInBlock;
    const int nWaves = gridDim.x * WPB;

    float local = 0.0f;
    for (int row = waveId; row < B; row += nWaves) {
        const size_t base = (size_t)row * D + (size_t)lane * 4;
        const float4 av = *(const float4*)(a + base);
        const float4 pv = *(const float4*)(p + base);
        const float4 nv = *(const float4*)(n + base);

        float d, sap, san, spn;
        d = av.x - pv.x; sap  = d * d;
        d = av.y - pv.y; sap += d * d;
        d = av.z - pv.z; sap += d * d;
        d = av.w - pv.w; sap += d * d;

        d = av.x - nv.x; san  = d * d;
        d = av.y - nv.y; san += d * d;
        d = av.z - nv.z; san += d * d;
        d = av.w - nv.w; san += d * d;

        d = pv.x - nv.x; spn  = d * d;
        d = pv.y - nv.y; spn += d * d;
        d = pv.z - nv.z; spn += d * d;
        d = pv.w - nv.w; spn += d * d;

        // butterfly reduce across the 64-lane wave
        #pragma unroll
        for (int off = 32; off > 0; off >>= 1) {
            sap += __shfl_xor(sap, off, 64);
            san += __shfl_xor(san, off, 64);
            spn += __shfl_xor(spn, off, 64);
        }

        if (lane == 0) {
            const float dap = sqrtf(sap);
            const float dan = sqrtf(san);
            const float dpn = sqrtf(spn);
            // margin_sim: exp(4*dap) ~ exp(90) -> inf -> term -> 0 (matches ref)
            const float msim = 1.0f + 2.0f / (__expf(4.0f * dap) + 1e-6f);
            // margin_dissim: exp(-4*dan+4) ~ exp(-86) << 1e-6 -> term ~ 2e6 (dominates)
            const float mdis = 1.0f + 2.0f / (__expf(-4.0f * dan + 4.0f) + 1e-6f);
            local += dap - 0.5f * (dan + dpn) + msim + mdis;
        }
    }

    __shared__ float sm[WPB];
    if (lane == 0) sm[waveInBlock] = local;
    __syncthreads();
    if (threadIdx.x == 0) {
        float s = 0.0f;
        #pragma unroll
        for (int i = 0; i < WPB; ++i) s += sm[i];
        partial[blockIdx.x] = s;
    }
}

__global__ __launch_bounds__(256) void final_reduce(
    const float* __restrict__ partial, float* __restrict__ out,
    int nPartial, float invB)
{
    float s = 0.0f;
    for (int i = threadIdx.x; i < nPartial; i += blockDim.x) s += partial[i];
    #pragma unroll
    for (int off = 32; off > 0; off >>= 1) s += __shfl_xor(s, off, 64);

    __shared__ float sm[4];
    const int lane = threadIdx.x & 63;
    const int w = threadIdx.x >> 6;
    if (lane == 0) sm[w] = s;
    __syncthreads();
    if (threadIdx.x == 0) out[0] = (sm[0] + sm[1] + sm[2] + sm[3]) * invB;
}

extern "C" void kernel_launch(void* const* d_in, const int* in_sizes, int n_in,
                              void* d_out, int out_size, void* d_ws, size_t ws_size,
                              hipStream_t stream) {
    const float* a = (const float*)d_in[0];
    const float* p = (const float*)d_in[1];
    const float* n = (const float*)d_in[2];
    float* out = (float*)d_out;
    float* partial = (float*)d_ws;   // NBLOCKS floats = 8 KiB scratch

    const int B = in_sizes[0] / D;   // 65536

    triplet_partial<<<NBLOCKS, TPB, 0, stream>>>(a, p, n, partial, B);
    final_reduce<<<1, 256, 0, stream>>>(partial, out, NBLOCKS, 1.0f / (float)B);
}

// Round 2
// 195.924 us; speedup vs baseline: 1.0009x; 1.0009x over previous
//
#include <hip/hip_runtime.h>
#include <math.h>

// AdaptiveTripletMarginLoss: B=65536 rows, D=256 fp32.
// R1: 16 lanes per row, 4 rows per wave, ONE iteration per wave.
//  - 12 independent float4 loads issued up front (MLP)
//  - one 4-step butterfly reduces all 4 rows at once (3 shuffles/row vs 18)

#define D 256
#define TPB 256
#define ROWS_PER_BLOCK 16   // 4 waves * 4 rows/wave

__global__ __launch_bounds__(TPB, 8) void triplet_partial(
    const float4* __restrict__ a4, const float4* __restrict__ p4,
    const float4* __restrict__ n4, float* __restrict__ partial, int B)
{
    const int lane = threadIdx.x & 63;
    const int waveInBlock = threadIdx.x >> 6;
    const int sub = lane >> 4;          // which of the wave's 4 rows
    const int sl  = lane & 15;          // lane within the 16-lane row group
    const int row = (blockIdx.x * 4 + waveInBlock) * 4 + sub;

    float sap = 0.0f, san = 0.0f, spn = 0.0f;

    if (row < B) {
        // row = 256 floats = 64 float4; 16 lanes * 4 chunks
        const size_t b = (size_t)row * 64 + sl;
        const float4 av0 = a4[b];      const float4 av1 = a4[b + 16];
        const float4 av2 = a4[b + 32]; const float4 av3 = a4[b + 48];
        const float4 pv0 = p4[b];      const float4 pv1 = p4[b + 16];
        const float4 pv2 = p4[b + 32]; const float4 pv3 = p4[b + 48];
        const float4 nv0 = n4[b];      const float4 nv1 = n4[b + 16];
        const float4 nv2 = n4[b + 32]; const float4 nv3 = n4[b + 48];

        float d;
#define ACC3(AV, PV, NV)                                                   \
        d = AV.x - PV.x; sap = fmaf(d, d, sap);                            \
        d = AV.y - PV.y; sap = fmaf(d, d, sap);                            \
        d = AV.z - PV.z; sap = fmaf(d, d, sap);                            \
        d = AV.w - PV.w; sap = fmaf(d, d, sap);                            \
        d = AV.x - NV.x; san = fmaf(d, d, san);                            \
        d = AV.y - NV.y; san = fmaf(d, d, san);                            \
        d = AV.z - NV.z; san = fmaf(d, d, san);                            \
        d = AV.w - NV.w; san = fmaf(d, d, san);                            \
        d = PV.x - NV.x; spn = fmaf(d, d, spn);                            \
        d = PV.y - NV.y; spn = fmaf(d, d, spn);                            \
        d = PV.z - NV.z; spn = fmaf(d, d, spn);                            \
        d = PV.w - NV.w; spn = fmaf(d, d, spn);

        ACC3(av0, pv0, nv0)
        ACC3(av1, pv1, nv1)
        ACC3(av2, pv2, nv2)
        ACC3(av3, pv3, nv3)
#undef ACC3
    }

    // butterfly over the 16-lane group: xor offsets 8,4,2,1 stay in-group.
    // One pass reduces all 4 rows of the wave simultaneously.
    #pragma unroll
    for (int off = 8; off >= 1; off >>= 1) {
        sap += __shfl_xor(sap, off, 64);
        san += __shfl_xor(san, off, 64);
        spn += __shfl_xor(spn, off, 64);
    }

    __shared__ float sm[ROWS_PER_BLOCK];
    if (sl == 0) {
        float v = 0.0f;
        if (row < B) {
            const float dap = sqrtf(sap);
            const float dan = sqrtf(san);
            const float dpn = sqrtf(spn);
            // exp(4*dap) ~ exp(90) -> inf -> term 0 (matches ref fp32)
            const float msim = 1.0f + 2.0f / (__expf(4.0f * dap) + 1e-6f);
            // exp(-4*dan+4) underflows vs 1e-6 -> term ~2e6 (dominates loss)
            const float mdis = 1.0f + 2.0f / (__expf(-4.0f * dan + 4.0f) + 1e-6f);
            v = dap - 0.5f * (dan + dpn) + msim + mdis;
        }
        sm[waveInBlock * 4 + sub] = v;
    }
    __syncthreads();
    if (threadIdx.x == 0) {
        float s = 0.0f;
        #pragma unroll
        for (int i = 0; i < ROWS_PER_BLOCK; ++i) s += sm[i];
        partial[blockIdx.x] = s;
    }
}

__global__ __launch_bounds__(256) void final_reduce(
    const float* __restrict__ partial, float* __restrict__ out,
    int nPartial, float invB)
{
    float s = 0.0f;
    for (int i = threadIdx.x; i < nPartial; i += blockDim.x) s += partial[i];
    #pragma unroll
    for (int off = 32; off > 0; off >>= 1) s += __shfl_xor(s, off, 64);

    __shared__ float sm[4];
    const int lane = threadIdx.x & 63;
    const int w = threadIdx.x >> 6;
    if (lane == 0) sm[w] = s;
    __syncthreads();
    if (threadIdx.x == 0) out[0] = (sm[0] + sm[1] + sm[2] + sm[3]) * invB;
}

extern "C" void kernel_launch(void* const* d_in, const int* in_sizes, int n_in,
                              void* d_out, int out_size, void* d_ws, size_t ws_size,
                              hipStream_t stream) {
    const float4* a = (const float4*)d_in[0];
    const float4* p = (const float4*)d_in[1];
    const float4* n = (const float4*)d_in[2];
    float* out = (float*)d_out;
    float* partial = (float*)d_ws;    // nBlocks floats (16 KiB) scratch

    const int B = in_sizes[0] / D;    // 65536
    const int nBlocks = (B + ROWS_PER_BLOCK - 1) / ROWS_PER_BLOCK;  // 4096

    triplet_partial<<<nBlocks, TPB, 0, stream>>>(a, p, n, partial, B);
    final_reduce<<<1, 256, 0, stream>>>(partial, out, nBlocks, 1.0f / (float)B);
}